// Round 5
// baseline (736.303 us; speedup 1.0000x reference)
//
#include <hip/hip_runtime.h>
#include <hip/hip_bf16.h>

// Fused Comm_OUT pipeline, batch-row-parallel (GRU recurrence is per-row).
// Round-5: packed bf16 weight streams live in a __device__ module global
// (g_wpk) instead of d_ws — rocprof showed d_ws loads miss L2 (~1 GB FETCH,
// HBM-latency per fragment) while identical-pattern d_in loads hit ~100%
// (round-2 FETCH = 20 MB). Module globals are ordinary cacheable VRAM.
// 256 blocks x 1024 threads (16 waves = rg(2) x cg(8)), BM=32 rows, 1/CU.
// Runtime dtype detection (inputs fp32 or bf16) via g_flag.

typedef __attribute__((ext_vector_type(8))) short bf16x8;   // 8 x bf16 (4 VGPRs)
typedef __attribute__((ext_vector_type(4))) float f32x4;    // MFMA accumulator

#define MFMA16(a, b, c) __builtin_amdgcn_mfma_f32_16x16x32_bf16((a), (b), (c), 0, 0, 0)

constexpr int F   = 640;
constexpr int H   = 256;
constexpr int LSTEPS = 20;
constexpr int CO  = 32;
constexpr int LDP = 264;   // padded bf16 row stride (16B-aligned rows)

// packed-weight element offsets inside g_wpk
constexpr size_t WHH_E  = 0;                    // 8cg*3g*8kk*2j*64lane*8 = 196608
constexpr size_t WIH_E  = 196608;               // 196608
constexpr size_t WC_E   = 393216;               // 8cg*8kk*2j*64*8       = 65536
constexpr size_t WMU_E  = 458752;               // 2w*8kk*64*8           = 8192
constexpr size_t WLIN_E = 466944;               // 8cg*20kk*2j*64*8      = 163840
constexpr size_t PK_ELEMS = 630784;

__device__ __align__(16) unsigned short g_wpk[PK_ELEMS];  // cacheable packed weights
__device__ int g_flag;                                    // 1 = inputs are fp32

__device__ __forceinline__ float bf2f(__hip_bfloat16 x) { return __bfloat162float(x); }
__device__ __forceinline__ unsigned short f2bs(float f) {
    __hip_bfloat16 h = __float2bfloat16(f);
    return *reinterpret_cast<unsigned short*>(&h);
}
__device__ __forceinline__ bf16x8 lds8(const unsigned short* p) {
    return *reinterpret_cast<const bf16x8*>(p);
}
__device__ __forceinline__ bf16x8 pk8(const unsigned short* base, size_t eoff) {
    return *reinterpret_cast<const bf16x8*>(base + eoff);
}
__device__ __forceinline__ float sigm(float x) {
    return 1.0f / (1.0f + __expf(-x));
}

template<bool F32>
__device__ __forceinline__ bf16x8 g8(const void* base, size_t off) {
    if constexpr (!F32) {
        return *reinterpret_cast<const bf16x8*>((const __hip_bfloat16*)base + off);
    } else {
        const float* f = (const float*)base + off;
        float4 lo = *reinterpret_cast<const float4*>(f);
        float4 hi = *reinterpret_cast<const float4*>(f + 4);
        bf16x8 r;
        r[0] = (short)f2bs(lo.x); r[1] = (short)f2bs(lo.y);
        r[2] = (short)f2bs(lo.z); r[3] = (short)f2bs(lo.w);
        r[4] = (short)f2bs(hi.x); r[5] = (short)f2bs(hi.y);
        r[6] = (short)f2bs(hi.z); r[7] = (short)f2bs(hi.w);
        return r;
    }
}

template<bool F32>
__device__ __forceinline__ float ld1(const void* base, int i) {
    if constexpr (!F32) return bf2f(((const __hip_bfloat16*)base)[i]);
    else                return ((const float*)base)[i];
}

// ---------------- dtype detect: v1 (uniform[0.5,1.5]) ----------------
__global__ void detect_dtype(const void* v1) {
    const unsigned short* u = (const unsigned short*)v1;
    int f32 = 0;
    for (int i = 0; i < 8; ++i) {
        unsigned short s = u[i];
        __hip_bfloat16 h = *reinterpret_cast<__hip_bfloat16*>(&s);
        float v = __bfloat162float(h);
        if (!(v >= 0.25f && v <= 2.0f)) f32 = 1;
    }
    g_flag = f32;
}

// ---------------- weight pre-pack (fp32|bf16 -> bf16 fragment streams) ----------------
__device__ __forceinline__ unsigned short cvt1(const void* p, size_t i, bool f32) {
    if (f32) return f2bs(((const float*)p)[i]);
    return ((const unsigned short*)p)[i];
}

__global__ void prepack(const void* Wlin, const void* Wih, const void* Whh,
                        const void* Wc, const void* Wmu) {
    const bool f32 = (g_flag != 0);
    const int gid = blockIdx.x * 256 + threadIdx.x;
    const void* src;
    size_t dbase;
    int row, col0, ncols;
    if (gid < 24576) {                       // Whh [768,256]
        int idx = gid;
        int lane = idx & 63, j = (idx >> 6) & 1, kk = (idx >> 7) & 7;
        int t2 = idx >> 10, g = t2 % 3, w = t2 / 3;
        row = g * 256 + w * 32 + j * 16 + (lane & 15);
        col0 = kk * 32 + (lane >> 4) * 8;
        ncols = 256; src = Whh; dbase = WHH_E + (size_t)idx * 8;
    } else if (gid < 49152) {                // Wih [768,256]
        int idx = gid - 24576;
        int lane = idx & 63, j = (idx >> 6) & 1, kk = (idx >> 7) & 7;
        int t2 = idx >> 10, g = t2 % 3, w = t2 / 3;
        row = g * 256 + w * 32 + j * 16 + (lane & 15);
        col0 = kk * 32 + (lane >> 4) * 8;
        ncols = 256; src = Wih; dbase = WIH_E + (size_t)idx * 8;
    } else if (gid < 57344) {                // Wc [256,256]
        int idx = gid - 49152;
        int lane = idx & 63, j = (idx >> 6) & 1, kk = (idx >> 7) & 7, w = idx >> 10;
        row = w * 32 + j * 16 + (lane & 15);
        col0 = kk * 32 + (lane >> 4) * 8;
        ncols = 256; src = Wc; dbase = WC_E + (size_t)idx * 8;
    } else if (gid < 58368) {                // Wmu [32,256]
        int idx = gid - 57344;
        int lane = idx & 63, kk = (idx >> 6) & 7, w = idx >> 9;
        row = w * 16 + (lane & 15);
        col0 = kk * 32 + (lane >> 4) * 8;
        ncols = 256; src = Wmu; dbase = WMU_E + (size_t)idx * 8;
    } else if (gid < 78848) {                // Wlin [256,640]
        int idx = gid - 58368;
        int lane = idx & 63, j = (idx >> 6) & 1;
        int t1 = idx >> 7, kk = t1 % 20, w = t1 / 20;
        row = w * 32 + j * 16 + (lane & 15);
        col0 = kk * 32 + (lane >> 4) * 8;
        ncols = 640; src = Wlin; dbase = WLIN_E + (size_t)idx * 8;
    } else {
        return;
    }
    const size_t s0 = (size_t)row * ncols + col0;
    #pragma unroll
    for (int i = 0; i < 8; ++i) g_wpk[dbase + i] = cvt1(src, s0 + i, f32);
}

// ---------------- FAST PATH: BM=32, 1024 threads, 256 blocks (1/CU) ----------------
template<bool F32>
__device__ __forceinline__ void fast_pipe(
    const void* hw, const void* blin,
    const void* g1, const void* be1, const void* m1, const void* v1, const void* a1,
    const void* bih, const void* bhh,
    const void* g2, const void* be2, const void* m2, const void* v2, const void* a2,
    const void* bc,
    const void* g3, const void* be3, const void* m3, const void* v3, const void* a3,
    const void* bmu,
    void* out,
    unsigned short* hb, unsigned short* yb, unsigned short* zb)
{
    const unsigned short* Wpk = g_wpk;
    const int tid  = threadIdx.x;
    const int w    = tid >> 6;        // wave 0..15
    const int cg   = w & 7;           // column group (32 cols)
    const int rg   = w >> 3;          // row group (16 rows)
    const int lane = tid & 63;
    const int m16  = lane & 15;
    const int q    = lane >> 4;
    const int row0 = blockIdx.x * 32;
    const int c0 = cg * 32 + m16;
    const int c1 = c0 + 16;
    const int cc2[2] = { c0, c1 };
    const size_t lane8 = (size_t)lane * 8;
    // per-block stream rotation; >>3 so blocks on one XCD (blockIdx%8) differ
    const int ro8  = (blockIdx.x >> 3) & 7;
    const int ro20 = ((blockIdx.x >> 3) * 7) % 20;

    // persistent per-step params (folded)
    float s2v[2], t2v[2], s3v[2], t3f[2], bhhn[2];
    #pragma unroll
    for (int j = 0; j < 2; ++j) {
        const int cc = cc2[j];
        float s;
        s = ld1<F32>(g2, cc) * rsqrtf(ld1<F32>(v2, cc) + 1e-5f);
        s2v[j] = s; t2v[j] = ld1<F32>(be2, cc) - ld1<F32>(m2, cc) * s;
        s = ld1<F32>(g3, cc) * rsqrtf(ld1<F32>(v3, cc) + 1e-5f);
        s3v[j] = s;
        t3f[j] = (ld1<F32>(bc, cc) - ld1<F32>(m3, cc)) * s + ld1<F32>(be3, cc);
        bhhn[j] = ld1<F32>(bhh, 2 * H + cc);
    }
    const float a2v = ld1<F32>(a2, 0), a3v = ld1<F32>(a3, 0);

    // ---- Phase 1: x = prelu(bn1(rows @ Wlin^T + blin)) -> yb (staging) ----
    {
        f32x4 xacc[2] = {};
        int kk = ro20;
        #pragma unroll
        for (int i = 0; i < 20; ++i) {
            bf16x8 a = g8<F32>(hw, (size_t)(row0 + rg * 16 + m16) * F + kk * 32 + q * 8);
            bf16x8 b0 = pk8(Wpk, WLIN_E + (size_t)((cg * 20 + kk) * 2 + 0) * 512 + lane8);
            bf16x8 b1 = pk8(Wpk, WLIN_E + (size_t)((cg * 20 + kk) * 2 + 1) * 512 + lane8);
            xacc[0] = MFMA16(a, b0, xacc[0]);
            xacc[1] = MFMA16(a, b1, xacc[1]);
            kk = (kk == 19) ? 0 : kk + 1;
        }
        #pragma unroll
        for (int j = 0; j < 2; ++j) {
            const int cc = cc2[j];
            float s = ld1<F32>(g1, cc) * rsqrtf(ld1<F32>(v1, cc) + 1e-5f);
            float t = ld1<F32>(be1, cc) - ld1<F32>(m1, cc) * s;
            float bl = ld1<F32>(blin, cc);
            float av = ld1<F32>(a1, 0);
            #pragma unroll
            for (int r = 0; r < 4; ++r) {
                float vv = (xacc[j][r] + bl) * s + t;
                vv = (vv >= 0.0f) ? vv : av * vv;
                yb[(rg * 16 + q * 4 + r) * LDP + cc] = f2bs(vv);
            }
        }
    }
    __syncthreads();   // x visible in yb

    // ---- Phase 2: gi = x @ Wih^T + (bih + bhh[r,z])  (registers) ----
    f32x4 gi[3][2] = {};
    {
        const unsigned short* xa = yb + (rg * 16 + m16) * LDP + q * 8;
        #pragma unroll
        for (int g = 0; g < 3; ++g) {
            int kk = ro8;
            #pragma unroll
            for (int i = 0; i < 8; ++i) {
                bf16x8 a = lds8(xa + kk * 32);
                bf16x8 b0 = pk8(Wpk, WIH_E + (size_t)(((cg * 3 + g) * 8 + kk) * 2 + 0) * 512 + lane8);
                bf16x8 b1 = pk8(Wpk, WIH_E + (size_t)(((cg * 3 + g) * 8 + kk) * 2 + 1) * 512 + lane8);
                gi[g][0] = MFMA16(a, b0, gi[g][0]);
                gi[g][1] = MFMA16(a, b1, gi[g][1]);
                kk = (kk + 1) & 7;
            }
        }
        #pragma unroll
        for (int g = 0; g < 3; ++g)
            #pragma unroll
            for (int j = 0; j < 2; ++j) {
                float bias = ld1<F32>(bih, g * H + cc2[j]);
                if (g < 2) bias += ld1<F32>(bhh, g * H + cc2[j]);
                #pragma unroll
                for (int r = 0; r < 4; ++r) gi[g][j][r] += bias;
            }
    }

    // ---- GRU loop + fused downstream ----
    // Barrier schedule per step t (single-buffered hb/yb/zb, windows disjoint):
    //  [gh reads hb(t-1)] [gates] A [write hb=h(t), yb=y(t)] B1
    //  [Wc reads yb; write zb=z(t)] B2 [Wmu reads zb -> out]
    float hreg[2][4] = {};
    const unsigned short* haP = hb + (rg * 16 + m16) * LDP + q * 8;
    const unsigned short* yaP = yb + (rg * 16 + m16) * LDP + q * 8;
    const int mto = (w >> 1) & 1;
    const int nto = w & 1;
    const unsigned short* zaP = zb + (mto * 16 + m16) * LDP + q * 8;
    const float bmuv = (w < 4) ? ld1<F32>(bmu, nto * 16 + m16) : 0.0f;

    #pragma unroll 1
    for (int t = 0; t < LSTEPS; ++t) {
        f32x4 gh[3][2] = {};
        if (t > 0) {
            #pragma unroll
            for (int g = 0; g < 3; ++g) {
                int kk = ro8;
                #pragma unroll
                for (int i = 0; i < 8; ++i) {
                    bf16x8 a = lds8(haP + kk * 32);
                    bf16x8 b0 = pk8(Wpk, WHH_E + (size_t)(((cg * 3 + g) * 8 + kk) * 2 + 0) * 512 + lane8);
                    bf16x8 b1 = pk8(Wpk, WHH_E + (size_t)(((cg * 3 + g) * 8 + kk) * 2 + 1) * 512 + lane8);
                    gh[g][0] = MFMA16(a, b0, gh[g][0]);
                    gh[g][1] = MFMA16(a, b1, gh[g][1]);
                    kk = (kk + 1) & 7;
                }
            }
        }
        // gates + h update + y = prelu(bn2(h))
        float yv[2][4];
        #pragma unroll
        for (int j = 0; j < 2; ++j)
            #pragma unroll
            for (int r = 0; r < 4; ++r) {
                float rr = sigm(gi[0][j][r] + gh[0][j][r]);
                float zz = sigm(gi[1][j][r] + gh[1][j][r]);
                float nin = gi[2][j][r] + rr * (gh[2][j][r] + bhhn[j]);
                float nn = 2.0f * sigm(2.0f * nin) - 1.0f;   // tanh
                float hh = (1.0f - zz) * nn + zz * hreg[j][r];
                hreg[j][r] = hh;
                float y = hh * s2v[j] + t2v[j];
                yv[j][r] = (y >= 0.0f) ? y : a2v * y;
            }
        __syncthreads();   // A: all reads of hb/yb/zb from prior phases done
        #pragma unroll
        for (int j = 0; j < 2; ++j)
            #pragma unroll
            for (int r = 0; r < 4; ++r) {
                const int idx = (rg * 16 + q * 4 + r) * LDP + cc2[j];
                hb[idx] = f2bs(hreg[j][r]);
                yb[idx] = f2bs(yv[j][r]);
            }
        __syncthreads();   // B1: h/y visible

        // w2 = y @ Wc^T -> z -> zb
        f32x4 w2[2] = {};
        {
            int kk = ro8;
            #pragma unroll
            for (int i = 0; i < 8; ++i) {
                bf16x8 a = lds8(yaP + kk * 32);
                bf16x8 b0 = pk8(Wpk, WC_E + (size_t)((cg * 8 + kk) * 2 + 0) * 512 + lane8);
                bf16x8 b1 = pk8(Wpk, WC_E + (size_t)((cg * 8 + kk) * 2 + 1) * 512 + lane8);
                w2[0] = MFMA16(a, b0, w2[0]);
                w2[1] = MFMA16(a, b1, w2[1]);
                kk = (kk + 1) & 7;
            }
        }
        #pragma unroll
        for (int j = 0; j < 2; ++j)
            #pragma unroll
            for (int r = 0; r < 4; ++r) {
                float z0 = w2[j][r] * s3v[j] + t3f[j];
                z0 = (z0 >= 0.0f) ? z0 : a3v * z0;
                zb[(rg * 16 + q * 4 + r) * LDP + cc2[j]] = f2bs(z0);
            }
        __syncthreads();   // B2: z visible

        // out_t = z @ Wmu^T + bmu   (waves 0..3 own the four 16x16 tiles)
        if (w < 4) {
            f32x4 o = {};
            int kk = ro8;
            #pragma unroll
            for (int i = 0; i < 8; ++i) {
                bf16x8 a = lds8(zaP + kk * 32);
                bf16x8 b = pk8(Wpk, WMU_E + (size_t)(nto * 8 + kk) * 512 + lane8);
                o = MFMA16(a, b, o);
                kk = (kk + 1) & 7;
            }
            #pragma unroll
            for (int r = 0; r < 4; ++r) {
                float vv = o[r] + bmuv;
                const size_t oi = (size_t)(row0 + mto * 16 + q * 4 + r) * (LSTEPS * CO)
                                + t * CO + nto * 16 + m16;
                if constexpr (F32) ((float*)out)[oi] = vv;
                else               ((__hip_bfloat16*)out)[oi] = __float2bfloat16(vv);
            }
        }
    }
}

__global__ __launch_bounds__(1024, 4) void comm_fast(
    const void* hw, const void* blin,
    const void* g1, const void* be1, const void* m1, const void* v1, const void* a1,
    const void* bih, const void* bhh,
    const void* g2, const void* be2, const void* m2, const void* v2, const void* a2,
    const void* bc,
    const void* g3, const void* be3, const void* m3, const void* v3, const void* a3,
    const void* bmu,
    void* out)
{
    __shared__ __align__(16) unsigned short hb[32 * LDP];
    __shared__ __align__(16) unsigned short yb[32 * LDP];
    __shared__ __align__(16) unsigned short zb[32 * LDP];
    if (g_flag) {
        fast_pipe<true >(hw, blin, g1, be1, m1, v1, a1, bih, bhh,
                         g2, be2, m2, v2, a2, bc, g3, be3, m3, v3, a3, bmu,
                         out, hb, yb, zb);
    } else {
        fast_pipe<false>(hw, blin, g1, be1, m1, v1, a1, bih, bhh,
                         g2, be2, m2, v2, a2, bc, g3, be3, m3, v3, a3, bmu,
                         out, hb, yb, zb);
    }
}

extern "C" void kernel_launch(void* const* d_in, const int* in_sizes, int n_in,
                              void* d_out, int out_size, void* d_ws, size_t ws_size,
                              hipStream_t stream) {
    (void)in_sizes; (void)n_in; (void)out_size; (void)d_ws; (void)ws_size;
    detect_dtype<<<dim3(1), dim3(1), 0, stream>>>(d_in[6]);
    prepack<<<dim3(308), dim3(256), 0, stream>>>(
        d_in[1], d_in[8], d_in[9], d_in[17], d_in[24]);
    comm_fast<<<dim3(256), dim3(1024), 0, stream>>>(
        d_in[0], d_in[2],
        d_in[3], d_in[4], d_in[5], d_in[6], d_in[7],
        d_in[10], d_in[11],
        d_in[12], d_in[13], d_in[14], d_in[15], d_in[16],
        d_in[18],
        d_in[19], d_in[20], d_in[21], d_in[22], d_in[23],
        d_in[25],
        d_out);
}